// Round 9
// baseline (232.532 us; speedup 1.0000x reference)
//
#include <hip/hip_runtime.h>
#include <math.h>

// Problem constants
//  B=64, CH=64, T_IN=32, N_OSC=32, BAND=16384, N_NOISE_FRAMES=4096, NOISE_STEP=4
//  N_UP=7, LOWEST_FREQ = 20/11025
#define LOWEST_FREQ_F 0.00181405895691609977f

typedef short bf16x8 __attribute__((ext_vector_type(8)));
typedef float f32x16 __attribute__((ext_vector_type(16)));

__device__ __forceinline__ float lrelu(float x) { return x > 0.f ? x : 0.2f * x; }
__device__ __forceinline__ float sin_rev(float fr) { return __builtin_amdgcn_sinf(fr); }
__device__ __forceinline__ float bf2f(unsigned short u) {
  union { unsigned int i; float f; } x; x.i = ((unsigned int)u) << 16; return x.f;
}
__device__ __forceinline__ unsigned short f2bf(float f) {
  union { float f; unsigned int i; } x; x.f = f;
  unsigned int r = x.i + 0x7FFFu + ((x.i >> 16) & 1u);   // RNE
  return (unsigned short)(r >> 16);
}
__device__ __forceinline__ unsigned int pack2(float a, float b) {
  return (unsigned int)f2bf(a) | ((unsigned int)f2bf(b) << 16);
}

// ---------------------------------------------------------------------------
// prep v2: LDS-staged, coalesced. One block per weight-layer (13 blocks).
// ---------------------------------------------------------------------------
__global__ __launch_bounds__(256) void prep_kernel(
    const float* __restrict__ net_w, const float* __restrict__ fin_w,
    const float* __restrict__ amp_w, const float* __restrict__ frq_w,
    const float* __restrict__ nzi_w, const float* __restrict__ nzu_w,
    float* __restrict__ wtF4, float* __restrict__ awfwT,
    float* __restrict__ nzT, short* __restrict__ wfold)
{
  __shared__ __align__(16) float wls[12288];   // 48 KB
  const int tid = threadIdx.x;
  const int bx  = blockIdx.x;

  if (bx < 7) {                 // ---- wfold layer bx ----
    const float4* src = (const float4*)(nzu_w + bx * 12288);
    #pragma unroll
    for (int i = 0; i < 12; ++i)
      ((float4*)wls)[tid + i*256] = src[tid + i*256];
    __syncthreads();
    short* dst = wfold + bx * 16384;
    for (int i = 0; i < 64; ++i) {
      int q = i*256 + tid;
      int pd = q >> 12, co = (q >> 6) & 63, ci = q & 63;
      const float* wb = wls + co*192 + ci*3;
      float v;
      if      (pd == 0) v = wb[0];
      else if (pd == 1) v = wb[1] + wb[2];
      else if (pd == 2) v = wb[0] + wb[1];
      else              v = wb[2];
      dst[q] = (short)f2bf(v);
    }
  } else if (bx < 12) {         // ---- wtF4 layer l ----
    int l = bx - 7;
    const float* s0 = (l < 4) ? (net_w + l * 12288) : fin_w;
    const float4* src = (const float4*)s0;
    #pragma unroll
    for (int i = 0; i < 12; ++i)
      ((float4*)wls)[tid + i*256] = src[tid + i*256];
    __syncthreads();
    float4* dst = ((float4*)wtF4) + l * 4096;
    for (int i = 0; i < 16; ++i) {
      int q = i*256 + tid;
      int ci = q >> 6, co = q & 63;
      const float* wb = wls + co*192 + ci*3;
      dst[q] = make_float4(wb[0], wb[1], wb[2], 0.f);
    }
  } else {                      // ---- awfwT + nzT ----
    #pragma unroll
    for (int i = 0; i < 2; ++i)
      ((float4*)wls)[tid + i*256] = ((const float4*)amp_w)[tid + i*256];
    #pragma unroll
    for (int i = 0; i < 2; ++i)
      ((float4*)(wls + 2048))[tid + i*256] = ((const float4*)frq_w)[tid + i*256];
    #pragma unroll
    for (int i = 0; i < 4; ++i)
      ((float4*)(wls + 4096))[tid + i*256] = ((const float4*)nzi_w)[tid + i*256];
    __syncthreads();
    for (int i = 0; i < 16; ++i) {
      int q = i*256 + tid;
      int c2 = q >> 7, rem = q & 127, o = rem >> 2, k = rem & 3;
      int c = c2*2 + (k >> 1);
      awfwT[q] = (k & 1) ? wls[2048 + o*64 + c] : wls[o*64 + c];
    }
    for (int i = 0; i < 16; ++i) {
      int q = i*256 + tid;
      int c = q >> 6, o = q & 63;
      nzT[q] = wls[4096 + o*64 + c];
    }
  }
}

// ---------------------------------------------------------------------------
// Generalized in-LDS up-conv stage with halo-exact masked stores.
// 512-thread version: 8 waves = 4 wave-pairs, tile n handled by pair (n&3).
// Per-tile FP ops and write locations identical to the 256-thread version
// => bitwise-identical results.
// v_mfma_f32_32x32x16_bf16 (HW-verified): A[m=L&31][k=(L>>5)*8+j],
// B[k][n=L&31], D col=L&31, row=(r&3)+8*(r>>2)+4*(L>>5).
// ---------------------------------------------------------------------------
template<int NT>
__device__ __forceinline__ void up_stage2(
    const short* bin, short* bout,
    const short* __restrict__ wf, const float* __restrict__ bias, int tid,
    int roff, int pairbase, int smin, int smax)
{
  const int L  = tid & 63;
  const int w  = tid >> 6;
  const int mt = w & 1;
  const int pg = w >> 1;   // 0..3

  bf16x8 Af[4][4];
  {
    const short* wb = wf + (mt*32 + (L & 31))*64 + ((L >> 5) << 3);
    #pragma unroll
    for (int pd = 0; pd < 4; ++pd)
      #pragma unroll
      for (int ks = 0; ks < 4; ++ks)
        Af[pd][ks] = *(const bf16x8*)(wb + pd*4096 + ks*16);
  }
  f32x16 binit;
  #pragma unroll
  for (int r = 0; r < 16; ++r)
    binit[r] = bias[mt*32 + (r & 3) + 8*(r >> 2) + 4*(L >> 5)];

  for (int n = pg; n < NT; n += 4) {
    int sl = n*32 + (L & 31);
    const short* bp = bin + (sl + roff)*72 + ((L >> 5) << 3);
    f32x16 Ce = binit, Co = binit;
    #pragma unroll
    for (int ks = 0; ks < 4; ++ks) {
      bf16x8 Bm = *(const bf16x8*)(bp + ks*16);
      bf16x8 B0 = *(const bf16x8*)(bp + 72 + ks*16);
      bf16x8 Bp = *(const bf16x8*)(bp + 144 + ks*16);
      Ce = __builtin_amdgcn_mfma_f32_32x32x16_bf16(Af[0][ks], Bm, Ce, 0, 0, 0);
      Ce = __builtin_amdgcn_mfma_f32_32x32x16_bf16(Af[1][ks], B0, Ce, 0, 0, 0);
      Co = __builtin_amdgcn_mfma_f32_32x32x16_bf16(Af[2][ks], B0, Co, 0, 0, 0);
      Co = __builtin_amdgcn_mfma_f32_32x32x16_bf16(Af[3][ks], Bp, Co, 0, 0, 0);
    }
    const int s0 = 2*(sl + pairbase);
    const bool we = (s0 >= smin)     && (s0 < smax);
    const bool wo = (s0 + 1 >= smin) && (s0 + 1 < smax);
    #pragma unroll
    for (int q4 = 0; q4 < 4; ++q4) {
      int co0 = mt*32 + 8*q4 + 4*(L >> 5);
      uint2 ve, vo;
      ve.x = pack2(lrelu(Ce[4*q4+0]), lrelu(Ce[4*q4+1]));
      ve.y = pack2(lrelu(Ce[4*q4+2]), lrelu(Ce[4*q4+3]));
      vo.x = pack2(lrelu(Co[4*q4+0]), lrelu(Co[4*q4+1]));
      vo.y = pack2(lrelu(Co[4*q4+2]), lrelu(Co[4*q4+3]));
      if (we) *(uint2*)&bout[(2*sl)*72 + co0]     = ve;
      if (wo) *(uint2*)&bout[(2*sl + 1)*72 + co0] = vo;
    }
  }
}

// ---------------------------------------------------------------------------
// Layer-6 stage with in-register nz_final coefficient projection (round-7
// verified): per lane, lrelu + 3-weight FMA over its 16 channels,
// shfl_xor(32) adds the complementary channel half (same frames), then 6
// scalar stores into cf[mt][3][512]. 512-thread: pairs take tiles n&3.
// ---------------------------------------------------------------------------
__device__ __forceinline__ void up_stage_coef(
    const short* bin, const short* __restrict__ wf,
    const float* __restrict__ bias, const float* __restrict__ wl4,
    float* __restrict__ cf, int tid)
{
  const int L  = tid & 63;
  const int w  = tid >> 6;
  const int mt = w & 1;
  const int pg = w >> 1;   // 0..3

  bf16x8 Af[4][4];
  {
    const short* wb = wf + (mt*32 + (L & 31))*64 + ((L >> 5) << 3);
    #pragma unroll
    for (int pd = 0; pd < 4; ++pd)
      #pragma unroll
      for (int ks = 0; ks < 4; ++ks)
        Af[pd][ks] = *(const bf16x8*)(wb + pd*4096 + ks*16);
  }
  f32x16 binit;
  #pragma unroll
  for (int r = 0; r < 16; ++r)
    binit[r] = bias[mt*32 + (r & 3) + 8*(r >> 2) + 4*(L >> 5)];

  for (int n = pg; n < 8; n += 4) {
    int sl = n*32 + (L & 31);                       // pair local, 0..255
    const short* bp = bin + (sl + 1)*72 + ((L >> 5) << 3);
    f32x16 Ce = binit, Co = binit;
    #pragma unroll
    for (int ks = 0; ks < 4; ++ks) {
      bf16x8 Bm = *(const bf16x8*)(bp + ks*16);
      bf16x8 B0 = *(const bf16x8*)(bp + 72 + ks*16);
      bf16x8 Bp = *(const bf16x8*)(bp + 144 + ks*16);
      Ce = __builtin_amdgcn_mfma_f32_32x32x16_bf16(Af[0][ks], Bm, Ce, 0, 0, 0);
      Ce = __builtin_amdgcn_mfma_f32_32x32x16_bf16(Af[1][ks], B0, Ce, 0, 0, 0);
      Co = __builtin_amdgcn_mfma_f32_32x32x16_bf16(Af[2][ks], B0, Co, 0, 0, 0);
      Co = __builtin_amdgcn_mfma_f32_32x32x16_bf16(Af[3][ks], Bp, Co, 0, 0, 0);
    }
    float c0e = 0.f, c1e = 0.f, c2e = 0.f;
    float c0o = 0.f, c1o = 0.f, c2o = 0.f;
    #pragma unroll
    for (int r = 0; r < 16; ++r) {
      int ch = mt*32 + 8*(r >> 2) + 4*(L >> 5) + (r & 3);
      float4 w4 = *(const float4*)&wl4[ch*4];
      float ye = lrelu(Ce[r]);
      float yo = lrelu(Co[r]);
      c0e = fmaf(w4.x, ye, c0e); c1e = fmaf(w4.y, ye, c1e); c2e = fmaf(w4.z, ye, c2e);
      c0o = fmaf(w4.x, yo, c0o); c1o = fmaf(w4.y, yo, c1o); c2o = fmaf(w4.z, yo, c2o);
    }
    c0e += __shfl_xor(c0e, 32, 64); c1e += __shfl_xor(c1e, 32, 64);
    c2e += __shfl_xor(c2e, 32, 64); c0o += __shfl_xor(c0o, 32, 64);
    c1o += __shfl_xor(c1o, 32, 64); c2o += __shfl_xor(c2o, 32, 64);
    if (L < 32) {
      int fe = 2*sl, fo = fe + 1;                   // local frame 0..511
      cf[mt*1536 + fe]        = c0e; cf[mt*1536 + 512 + fe]  = c1e;
      cf[mt*1536 + 1024 + fe] = c2e;
      cf[mt*1536 + fo]        = c0o; cf[mt*1536 + 512 + fo]  = c1o;
      cf[mt*1536 + 1024 + fo] = c2o;
    }
  }
}

// ---------------------------------------------------------------------------
// up_osc: noise layers 0..6 + coeff projection + noise filter + oscillator
// bank, fully fused (y0 T=32 -> out), 512 threads. Block (bx, b), bx in
// [0,8): frames [512bx, 512bx+512), one frame per thread in the epilogue.
// Halo chain (exact, verified r7/r8): y0 [4bx-2,4bx+10) -> y1 [8bx-2,8bx+18)
// -> y2 [16bx-2,16bx+33) -> y3 [32bx-2,32bx+64) -> y4 [64bx-2,64bx+126) ->
// y5 [128bx-2,128bx+190) -> y6 [256bx-2,256bx+258) -> coeffs. s6 (260 rows)
// overlays dead y0b..s4 (re-zeroed); cf overlays dead s5; al/fqv/pl overlay
// dead s6 after the coef stage. Stores masked to true layer length =>
// identical to the unfused zero-halo chain.
// ---------------------------------------------------------------------------
__global__ __launch_bounds__(512, 4) void up_osc(
    const unsigned short* __restrict__ y0g,
    const short* __restrict__ wfold, const float* __restrict__ nzu_b,
    const float* __restrict__ nzf_w, const float* __restrict__ nzf_b,
    const float* __restrict__ noise,
    const float* __restrict__ amp, const float* __restrict__ frq,
    const float* __restrict__ ph, float* __restrict__ out)
{
  // rows: y0b 34 | y1b 35 | y2b 66 | s3 66 | s4 128 | s5 192  (x72 shorts)
  __shared__ __align__(16) short arena[521 * 72];   // 75024 B
  __shared__ float wl4[256];                        // [c]{w0,w1,w2,0}
  short* y0b = arena;                //  34 rows
  short* y1b = arena + 34*72;        //  35 rows
  short* y2b = arena + 69*72;        //  66 rows
  short* s3  = arena + 135*72;       //  66 rows
  short* s4  = arena + 201*72;       // 128 rows
  short* s5  = arena + 329*72;       // 192 rows
  short* s6  = arena;                // 260 rows, overlays y0b..s4 (phase 2)
  float* cf  = (float*)(arena + 329*72);  // 3072 f32, overlays s5 (phase 3)
  float* al  = (float*)arena;             // 1024 f32, overlays s6 (phase 4)
  float* fqv = (float*)arena + 1024;
  float* pl  = (float*)arena + 2048;

  const int b   = blockIdx.y;
  const int bx  = blockIdx.x;    // 0..7
  const int tid = threadIdx.x;

  if (tid < 64) {
    wl4[tid*4 + 0] = nzf_w[tid];
    wl4[tid*4 + 1] = nzf_w[64 + tid];
    wl4[tid*4 + 2] = nzf_w[128 + tid];
    wl4[tid*4 + 3] = 0.f;
  }
  // zero-init arena (4689 uint4)
  for (int i = tid; i < 4689; i += 512) ((uint4*)arena)[i] = make_uint4(0,0,0,0);
  __syncthreads();

  // stage y0 tile: row r <- sample 4bx-2+r (only valid samples loaded)
  const unsigned short* inb = y0g + (size_t)b * 32 * 64;
  for (int c = tid; c < 34*8; c += 512) {
    int row = c >> 3, pos = (c & 7) << 3;
    int g = 4*bx - 2 + row;
    if (g >= 0 && g < 32)
      *(bf16x8*)&y0b[row*72 + pos] = *(const bf16x8*)(inb + (size_t)g*64 + pos);
  }
  __syncthreads();

  int lo, hi;
  lo = 8*bx - 2;   hi = 8*bx + 18;
  up_stage2<1>(y0b, y1b, wfold + 0*16384, nzu_b + 0*64, tid,
               0, 4*bx - 1, lo < 0 ? 0 : lo, hi > 64 ? 64 : hi);
  __syncthreads();
  lo = 16*bx - 2;  hi = 16*bx + 33;
  up_stage2<1>(y1b, y2b, wfold + 1*16384, nzu_b + 1*64, tid,
               0, 8*bx - 1, lo < 0 ? 0 : lo, hi > 128 ? 128 : hi);
  __syncthreads();
  lo = 32*bx - 2;  hi = 32*bx + 64;
  up_stage2<2>(y2b, s3, wfold + 2*16384, nzu_b + 2*64, tid,
               0, 16*bx - 1, lo < 0 ? 0 : lo, hi > 256 ? 256 : hi);
  __syncthreads();
  lo = 64*bx - 2;  hi = 64*bx + 126;
  up_stage2<2>(s3, s4, wfold + 3*16384, nzu_b + 3*64, tid,
               0, 32*bx - 1, lo < 0 ? 0 : lo, hi > 512 ? 512 : hi);
  __syncthreads();
  lo = 128*bx - 2; hi = 128*bx + 190;
  up_stage2<3>(s4, s5, wfold + 4*16384, nzu_b + 4*64, tid,
               0, 64*bx - 1, lo < 0 ? 0 : lo, hi > 1024 ? 1024 : hi);
  __syncthreads();

  // re-zero s6 region (260 rows overlay dead y0b..s4) while s5 holds y5
  for (int i = tid; i < 2340; i += 512) ((uint4*)arena)[i] = make_uint4(0,0,0,0);
  __syncthreads();

  // layer 5 -> s6: pairs [128bx-1, 128bx+129), y6 samples [256bx-2,256bx+258)
  hi = 256*bx + 258;
  up_stage2<5>(s5, s6, wfold + 5*16384, nzu_b + 5*64, tid,
               0, 128*bx - 1, 0, hi > 2048 ? 2048 : hi);
  __syncthreads();

  // layer 6 + coeff projection -> cf (overlays dead s5)
  up_stage_coef(s6, wfold + 6*16384, nzu_b + 6*64, wl4, cf, tid);
  __syncthreads();

  // stage amp/frq/ph into the dead s6 overlay
  for (int i = tid; i < 1024; i += 512) {
    al[i]  = amp[b*1024 + i];
    fqv[i] = frq[b*1024 + i];
    pl[i]  = ph[b*1024 + i];
  }
  __syncthreads();

  // ---- epilogue: one thread per frame (local frame = tid) ----
  {
    float c0 = nzf_b[0] + cf[tid]        + cf[1536 + tid];
    float c1 = nzf_b[1] + cf[512 + tid]  + cf[1536 + 512 + tid];
    float c2 = nzf_b[2] + cf[1024 + tid] + cf[1536 + 1024 + tid];
    c0 *= c0; c1 *= c1; c2 *= c2;

    const int fb = 512*bx + tid;               // frame in [0,4096)
    const size_t base = (size_t)b*4096 + fb;
    const float4 n = *(const float4*)(noise + base*4);
    float F0  = c0 * (n.x + n.y + n.z + n.w) * 0.5f;
    float F1r = c1 * (n.x - n.z) * 0.5f;
    float F1i = -(c1 * (n.y - n.w) * 0.5f);
    float F2  = c2 * (n.x - n.y + n.z - n.w) * 0.5f;
    float r0 = 0.5f * (F0 + 2.f*F1r + F2);
    float r1 = 0.5f * (F0 - 2.f*F1i - F2);
    float r2 = 0.5f * (F0 - 2.f*F1r + F2);
    float r3 = 0.5f * (F0 + 2.f*F1i - F2);

    const int t0 = fb * 4;
    float s0a = 0.f, s1a = 0.f, s2a = 0.f, s3a = 0.f;
    if (t0 < 256) {                      // head: freq=f0, amp=a0
      const float tp = (float)(t0 + 1) * 0.5f;
      #pragma unroll 4
      for (int o = 0; o < 32; ++o) {
        float f0 = fqv[o*32], am = al[o*32];
        float hf = 0.5f * f0;
        float v0 = tp * f0, v1 = v0 + hf, v2 = v1 + hf, v3 = v2 + hf;
        s0a += am * sin_rev(v0 - floorf(v0));
        s1a += am * sin_rev(v1 - floorf(v1));
        s2a += am * sin_rev(v2 - floorf(v2));
        s3a += am * sin_rev(v3 - floorf(v3));
      }
    } else if (t0 >= 16128) {            // tail: freq=f31, amp=a31
      const float tp = (float)(t0 - 16127) * 0.5f;
      #pragma unroll 4
      for (int o = 0; o < 32; ++o) {
        float f0 = fqv[o*32 + 31], am = al[o*32 + 31], p = pl[o*32 + 31];
        float hf = 0.5f * f0;
        float v0 = p + tp * f0, v1 = v0 + hf, v2 = v1 + hf, v3 = v2 + hf;
        s0a += am * sin_rev(v0 - floorf(v0));
        s1a += am * sin_rev(v1 - floorf(v1));
        s2a += am * sin_rev(v2 - floorf(v2));
        s3a += am * sin_rev(v3 - floorf(v3));
      }
    } else {                             // middle: same interp cell for all 4
      const int i  = (t0 - 256) >> 9;
      const int m0 = (t0 - 256) & 511;
      float mm[4], fa[4], mq[4];
      #pragma unroll
      for (int js = 0; js < 4; ++js) {
        float mmv = (float)(m0 + 1 + js);
        mm[js] = mmv;
        fa[js] = ((float)(m0 + js) + 0.5f) * (1.f/512.f);
        mq[js] = mmv * mmv * (1.f/1024.f);
      }
      #pragma unroll 4
      for (int o = 0; o < 32; ++o) {
        float f0 = fqv[o*32 + i], f1 = fqv[o*32 + i + 1];
        float a0 = al[o*32 + i],  a1 = al[o*32 + i + 1];
        float p  = pl[o*32 + i];
        float df = f1 - f0, da = a1 - a0;
        #pragma unroll
        for (int js = 0; js < 4; ++js) {
          float av   = fmaf(da, fa[js], a0);
          float part = fmaf(df, mq[js], mm[js] * f0);
          float v    = fmaf(part, 0.5f, p);
          float fr   = v - floorf(v);
          float sv   = av * sin_rev(fr);
          if      (js == 0) s0a += sv;
          else if (js == 1) s1a += sv;
          else if (js == 2) s2a += sv;
          else              s3a += sv;
        }
      }
    }
    float4 res = make_float4(s0a + r0, s1a + r1, s2a + r2, s3a + r3);
    *(float4*)(out + base*4) = res;
  }
}

// ---------------------------------------------------------------------------
// Conv-stack helpers: 8-ci chunk register double-buffer for weights (global,
// VMEM pipe) AND z rows (LDS). All indices compile-time after inlining.
// ---------------------------------------------------------------------------
__device__ __forceinline__ void load_w8(float4* W, const float4* wp, int cc) {
  #pragma unroll
  for (int k = 0; k < 8; ++k) W[k] = wp[(cc*8 + k)*64];
}
__device__ __forceinline__ void load_z8(float* Z, const float* pa, int cc, int t0) {
  #pragma unroll
  for (int k = 0; k < 8; ++k) {
    const float* r = pa + (cc*8 + k)*36 + t0;
    float4 a = *(const float4*)r;
    float2 b2 = *(const float2*)(r + 4);
    Z[k*6+0] = a.x; Z[k*6+1] = a.y; Z[k*6+2] = a.z;
    Z[k*6+3] = a.w; Z[k*6+4] = b2.x; Z[k*6+5] = b2.y;
  }
}
__device__ __forceinline__ void fma8(float* acc, const float4* W, const float* Z) {
  #pragma unroll
  for (int k = 0; k < 8; ++k) {
    #pragma unroll
    for (int j = 0; j < 4; ++j) {
      acc[j] = fmaf(W[k].x, Z[k*6+j],   acc[j]);
      acc[j] = fmaf(W[k].y, Z[k*6+j+1], acc[j]);
      acc[j] = fmaf(W[k].z, Z[k*6+j+2], acc[j]);
    }
  }
}

// ---------------------------------------------------------------------------
// z_front v3: 512 threads/block, one block per batch. Conv stack only (plus
// y0 / amp / freq / fp64-phase). Noise layers live in up_osc.
// ---------------------------------------------------------------------------
__global__ __launch_bounds__(512, 2) void z_front(
    const float* __restrict__ x, const float* __restrict__ wtF4,
    const float* __restrict__ net_b, const float* __restrict__ fin_b,
    const float* __restrict__ awfwT, const float* __restrict__ amp_b,
    const float* __restrict__ frq_b,
    const float* __restrict__ nzT, const float* __restrict__ nzi_b,
    unsigned short* __restrict__ y0g, float* __restrict__ amp_o,
    float* __restrict__ frq_o, float* __restrict__ ph_o)
{
  // arena (31104 B): za [0,9216) | zb [9216,18432) | zt [18432,26880)
  //                  fl [26880,31104)
  __shared__ __align__(16) char arena[31104];
  float* za = (float*)arena;
  float* zb = (float*)(arena + 9216);
  float* zt = (float*)(arena + 18432);
  float* fl = (float*)(arena + 26880);

  const int b   = blockIdx.x;
  const int tid = threadIdx.x;
  const int co  = tid & 63;
  const int wv  = tid >> 6;   // 0..7

  // stage input (rows shifted +1: za[c][s] = x[c][s-1]); zero halos
  for (int idx = tid; idx < 2048; idx += 512) {
    int t = idx >> 6, c = idx & 63;
    za[c*36 + t + 1] = x[b*2048 + idx];
  }
  if (tid < 64) {
    za[tid*36] = 0.f; za[tid*36 + 33] = 0.f;
    zb[tid*36] = 0.f; zb[tid*36 + 33] = 0.f;
  }
  __syncthreads();

  // ---- conv stack: 8 waves, 4 t/thread, dual (w,z) 8-ci double-buffer ----
  float* pa = za;
  float* pb = zb;
  for (int l = 0; l < 5; ++l) {
    {
      const int t0 = wv << 2;
      float bv = (l < 4) ? net_b[l*64 + co] : fin_b[co];
      float acc[4];
      #pragma unroll
      for (int j = 0; j < 4; ++j) acc[j] = bv;

      const float4* wp = ((const float4*)wtF4) + l*4096 + co;  // [ci*64]
      float4 wA[8], wB[8];
      float  zA[48], zB[48];
      load_w8(wA, wp, 0);
      load_z8(zA, pa, 0, t0);

      #pragma unroll
      for (int cc = 0; cc < 8; ++cc) {
        if (cc & 1) {
          if (cc < 7) { load_w8(wA, wp, cc + 1); load_z8(zA, pa, cc + 1, t0); }
          fma8(acc, wB, zB);
        } else {
          if (cc < 7) { load_w8(wB, wp, cc + 1); load_z8(zB, pa, cc + 1, t0); }
          fma8(acc, wA, zA);
        }
      }

      if (l < 4) {
        #pragma unroll
        for (int j = 0; j < 4; ++j)
          pb[co*36 + t0 + j + 1] = lrelu(acc[j]);
      } else {
        // final z: store UNSHIFTED (cols 0..31) + transposed copy for proj
        #pragma unroll
        for (int j = 0; j < 4; ++j) {
          int t = t0 + j;
          pb[co*36 + t] = acc[j];
          zt[t*66 + co] = acc[j];
        }
      }
    }
    __syncthreads();
    float* tp = pa; pa = pb; pb = tp;
  }
  const float* zf = pa;  // final z, 64ch x 32t, cols 0..31 (no halo shift)

  // ---- y0 = nz_init 1x1 conv -> bf16 -> GLOBAL [b][t][co] ----
  {
    const int q = wv;          // 0..7, t = q*4..q*4+3
    float bv0 = nzi_b[co];
    float acc[4];
    #pragma unroll
    for (int j = 0; j < 4; ++j) acc[j] = bv0;
    #pragma unroll 8
    for (int c = 0; c < 64; ++c) {
      float4 zv = *(const float4*)(zf + c*36 + (q << 2));
      float wvv = nzT[c*64 + co];
      acc[0] = fmaf(wvv, zv.x, acc[0]);
      acc[1] = fmaf(wvv, zv.y, acc[1]);
      acc[2] = fmaf(wvv, zv.z, acc[2]);
      acc[3] = fmaf(wvv, zv.w, acc[3]);
    }
    unsigned short* yb = y0g + (size_t)b * 2048;
    #pragma unroll
    for (int j = 0; j < 4; ++j)
      yb[((q << 2) + j)*64 + co] = f2bf(acc[j]);
  }

  // ---- amp / freq projections: global paired b128 weights + zt b64 reads ---
  #pragma unroll
  for (int tt = 0; tt < 2; ++tt) {
    int task = tid + 512*tt;
    int o = task & 31, t = task >> 5;
    float aa = amp_b[o], ff = frq_b[o];
    #pragma unroll 8
    for (int c2 = 0; c2 < 32; ++c2) {
      float4 w4 = ((const float4*)awfwT)[c2*32 + o];
      float2 zv = *(const float2*)(zt + t*66 + c2*2);
      aa = fmaf(w4.x, zv.x, aa); ff = fmaf(w4.y, zv.x, ff);
      aa = fmaf(w4.z, zv.y, aa); ff = fmaf(w4.w, zv.y, ff);
    }
    aa = fabsf(aa);
    float sg = 1.f / (1.f + expf(-ff));
    float fq = LOWEST_FREQ_F + sg * (1.f - LOWEST_FREQ_F);
    amp_o[b*1024 + o*32 + t] = aa;
    frq_o[b*1024 + o*32 + t] = fq;
    fl[o*33 + t] = fq;
  }
  __syncthreads();

  // ---- fp64 phase boundary prefix on wave 7 ----
  if (wv == 7 && (tid & 63) < 32) {
    const int o = tid & 31;
    double P = 256.0 * (double)fl[o*33];
    double hd = P * 0.5;
    ph_o[b*1024 + o*32] = (float)(hd - floor(hd));
    for (int i = 1; i < 32; ++i) {
      P += 256.0 * ((double)fl[o*33 + i - 1] + (double)fl[o*33 + i]);
      hd = P * 0.5;
      ph_o[b*1024 + o*32 + i] = (float)(hd - floor(hd));
    }
  }
}

// ---------------------------------------------------------------------------
extern "C" void kernel_launch(void* const* d_in, const int* in_sizes, int n_in,
                              void* d_out, int out_size, void* d_ws, size_t ws_size,
                              hipStream_t stream) {
  (void)in_sizes; (void)n_in; (void)out_size; (void)ws_size;
  const float* x     = (const float*)d_in[0];
  const float* noise = (const float*)d_in[1];
  const float* net_w = (const float*)d_in[2];
  const float* net_b = (const float*)d_in[3];
  const float* fin_w = (const float*)d_in[4];
  const float* fin_b = (const float*)d_in[5];
  const float* amp_w = (const float*)d_in[6];
  const float* amp_b = (const float*)d_in[7];
  const float* frq_w = (const float*)d_in[8];
  const float* frq_b = (const float*)d_in[9];
  const float* nzi_w = (const float*)d_in[10];
  const float* nzi_b = (const float*)d_in[11];
  const float* nzu_w = (const float*)d_in[12];
  const float* nzu_b = (const float*)d_in[13];
  const float* nzf_w = (const float*)d_in[14];
  const float* nzf_b = (const float*)d_in[15];
  float* out = (float*)d_out;

  // workspace (~2 MiB)
  short* y0    = (short*)d_ws;                       // 64*32*64
  short* wfold = y0 + (size_t)64*32*64;              // 7*16384
  float* wtF4  = (float*)(wfold + 7*16384);          // 5*4096*4 = 81920
  float* awfwT = wtF4 + 81920;                       // 4096
  float* nzT   = awfwT + 4096;                       // 4096
  float* ampv  = nzT + 4096;                         // 65536
  float* frqv  = ampv + 65536;                       // 65536
  float* phv   = frqv + 65536;                       // 65536

  prep_kernel<<<dim3(13), dim3(256), 0, stream>>>(
      net_w, fin_w, amp_w, frq_w, nzi_w, nzu_w, wtF4, awfwT, nzT, wfold);

  z_front<<<dim3(64), dim3(512), 0, stream>>>(
      x, wtF4, net_b, fin_b, awfwT, amp_b, frq_b, nzT, nzi_b,
      (unsigned short*)y0, ampv, frqv, phv);

  up_osc<<<dim3(8, 64), dim3(512), 0, stream>>>(
      (unsigned short*)y0, wfold, nzu_b, nzf_w, nzf_b,
      noise, ampv, frqv, phv, out);
}

// Round 10
// 197.382 us; speedup vs baseline: 1.1781x; 1.1781x over previous
//
#include <hip/hip_runtime.h>
#include <math.h>

// Problem constants
//  B=64, CH=64, T_IN=32, N_OSC=32, BAND=16384, N_NOISE_FRAMES=4096, NOISE_STEP=4
//  N_UP=7, LOWEST_FREQ = 20/11025
#define LOWEST_FREQ_F 0.00181405895691609977f

typedef short bf16x8 __attribute__((ext_vector_type(8)));
typedef float f32x16 __attribute__((ext_vector_type(16)));

__device__ __forceinline__ float lrelu(float x) { return x > 0.f ? x : 0.2f * x; }
__device__ __forceinline__ float sin_rev(float fr) { return __builtin_amdgcn_sinf(fr); }
__device__ __forceinline__ float bf2f(unsigned short u) {
  union { unsigned int i; float f; } x; x.i = ((unsigned int)u) << 16; return x.f;
}
__device__ __forceinline__ unsigned short f2bf(float f) {
  union { float f; unsigned int i; } x; x.f = f;
  unsigned int r = x.i + 0x7FFFu + ((x.i >> 16) & 1u);   // RNE
  return (unsigned short)(r >> 16);
}
__device__ __forceinline__ unsigned int pack2(float a, float b) {
  return (unsigned int)f2bf(a) | ((unsigned int)f2bf(b) << 16);
}

// ---------------------------------------------------------------------------
// prep v2: LDS-staged, coalesced. One block per weight-layer (13 blocks).
// ---------------------------------------------------------------------------
__global__ __launch_bounds__(256) void prep_kernel(
    const float* __restrict__ net_w, const float* __restrict__ fin_w,
    const float* __restrict__ amp_w, const float* __restrict__ frq_w,
    const float* __restrict__ nzi_w, const float* __restrict__ nzu_w,
    float* __restrict__ wtF4, float* __restrict__ awfwT,
    float* __restrict__ nzT, short* __restrict__ wfold)
{
  __shared__ __align__(16) float wls[12288];   // 48 KB
  const int tid = threadIdx.x;
  const int bx  = blockIdx.x;

  if (bx < 7) {                 // ---- wfold layer bx ----
    const float4* src = (const float4*)(nzu_w + bx * 12288);
    #pragma unroll
    for (int i = 0; i < 12; ++i)
      ((float4*)wls)[tid + i*256] = src[tid + i*256];
    __syncthreads();
    short* dst = wfold + bx * 16384;
    for (int i = 0; i < 64; ++i) {
      int q = i*256 + tid;
      int pd = q >> 12, co = (q >> 6) & 63, ci = q & 63;
      const float* wb = wls + co*192 + ci*3;
      float v;
      if      (pd == 0) v = wb[0];
      else if (pd == 1) v = wb[1] + wb[2];
      else if (pd == 2) v = wb[0] + wb[1];
      else              v = wb[2];
      dst[q] = (short)f2bf(v);
    }
  } else if (bx < 12) {         // ---- wtF4 layer l ----
    int l = bx - 7;
    const float* s0 = (l < 4) ? (net_w + l * 12288) : fin_w;
    const float4* src = (const float4*)s0;
    #pragma unroll
    for (int i = 0; i < 12; ++i)
      ((float4*)wls)[tid + i*256] = src[tid + i*256];
    __syncthreads();
    float4* dst = ((float4*)wtF4) + l * 4096;
    for (int i = 0; i < 16; ++i) {
      int q = i*256 + tid;
      int ci = q >> 6, co = q & 63;
      const float* wb = wls + co*192 + ci*3;
      dst[q] = make_float4(wb[0], wb[1], wb[2], 0.f);
    }
  } else {                      // ---- awfwT + nzT ----
    #pragma unroll
    for (int i = 0; i < 2; ++i)
      ((float4*)wls)[tid + i*256] = ((const float4*)amp_w)[tid + i*256];
    #pragma unroll
    for (int i = 0; i < 2; ++i)
      ((float4*)(wls + 2048))[tid + i*256] = ((const float4*)frq_w)[tid + i*256];
    #pragma unroll
    for (int i = 0; i < 4; ++i)
      ((float4*)(wls + 4096))[tid + i*256] = ((const float4*)nzi_w)[tid + i*256];
    __syncthreads();
    for (int i = 0; i < 16; ++i) {
      int q = i*256 + tid;
      int c2 = q >> 7, rem = q & 127, o = rem >> 2, k = rem & 3;
      int c = c2*2 + (k >> 1);
      awfwT[q] = (k & 1) ? wls[2048 + o*64 + c] : wls[o*64 + c];
    }
    for (int i = 0; i < 16; ++i) {
      int q = i*256 + tid;
      int c = q >> 6, o = q & 63;
      nzT[q] = wls[4096 + o*64 + c];
    }
  }
}

// ---------------------------------------------------------------------------
// Generalized in-LDS up-conv stage with halo-exact masked stores.
// 512-thread version: 8 waves = 4 wave-pairs, tile n handled by pair (n&3).
// Per-tile FP ops and write locations identical to the 256-thread version
// => bitwise-identical results.
// v_mfma_f32_32x32x16_bf16 (HW-verified): A[m=L&31][k=(L>>5)*8+j],
// B[k][n=L&31], D col=L&31, row=(r&3)+8*(r>>2)+4*(L>>5).
// ---------------------------------------------------------------------------
template<int NT>
__device__ __forceinline__ void up_stage2(
    const short* bin, short* bout,
    const short* __restrict__ wf, const float* __restrict__ bias, int tid,
    int roff, int pairbase, int smin, int smax)
{
  const int L  = tid & 63;
  const int w  = tid >> 6;
  const int mt = w & 1;
  const int pg = w >> 1;   // 0..3

  bf16x8 Af[4][4];
  {
    const short* wb = wf + (mt*32 + (L & 31))*64 + ((L >> 5) << 3);
    #pragma unroll
    for (int pd = 0; pd < 4; ++pd)
      #pragma unroll
      for (int ks = 0; ks < 4; ++ks)
        Af[pd][ks] = *(const bf16x8*)(wb + pd*4096 + ks*16);
  }
  f32x16 binit;
  #pragma unroll
  for (int r = 0; r < 16; ++r)
    binit[r] = bias[mt*32 + (r & 3) + 8*(r >> 2) + 4*(L >> 5)];

  for (int n = pg; n < NT; n += 4) {
    int sl = n*32 + (L & 31);
    const short* bp = bin + (sl + roff)*72 + ((L >> 5) << 3);
    f32x16 Ce = binit, Co = binit;
    #pragma unroll
    for (int ks = 0; ks < 4; ++ks) {
      bf16x8 Bm = *(const bf16x8*)(bp + ks*16);
      bf16x8 B0 = *(const bf16x8*)(bp + 72 + ks*16);
      bf16x8 Bp = *(const bf16x8*)(bp + 144 + ks*16);
      Ce = __builtin_amdgcn_mfma_f32_32x32x16_bf16(Af[0][ks], Bm, Ce, 0, 0, 0);
      Ce = __builtin_amdgcn_mfma_f32_32x32x16_bf16(Af[1][ks], B0, Ce, 0, 0, 0);
      Co = __builtin_amdgcn_mfma_f32_32x32x16_bf16(Af[2][ks], B0, Co, 0, 0, 0);
      Co = __builtin_amdgcn_mfma_f32_32x32x16_bf16(Af[3][ks], Bp, Co, 0, 0, 0);
    }
    const int s0 = 2*(sl + pairbase);
    const bool we = (s0 >= smin)     && (s0 < smax);
    const bool wo = (s0 + 1 >= smin) && (s0 + 1 < smax);
    #pragma unroll
    for (int q4 = 0; q4 < 4; ++q4) {
      int co0 = mt*32 + 8*q4 + 4*(L >> 5);
      uint2 ve, vo;
      ve.x = pack2(lrelu(Ce[4*q4+0]), lrelu(Ce[4*q4+1]));
      ve.y = pack2(lrelu(Ce[4*q4+2]), lrelu(Ce[4*q4+3]));
      vo.x = pack2(lrelu(Co[4*q4+0]), lrelu(Co[4*q4+1]));
      vo.y = pack2(lrelu(Co[4*q4+2]), lrelu(Co[4*q4+3]));
      if (we) *(uint2*)&bout[(2*sl)*72 + co0]     = ve;
      if (wo) *(uint2*)&bout[(2*sl + 1)*72 + co0] = vo;
    }
  }
}

// ---------------------------------------------------------------------------
// Layer-6 stage with in-register nz_final coefficient projection (round-7
// verified): per lane, lrelu + 3-weight FMA over its 16 channels,
// shfl_xor(32) adds the complementary channel half (same frames), then 6
// scalar stores into cf[mt][3][512]. 512-thread: pairs take tiles n&3.
// ---------------------------------------------------------------------------
__device__ __forceinline__ void up_stage_coef(
    const short* bin, const short* __restrict__ wf,
    const float* __restrict__ bias, const float* __restrict__ wl4,
    float* __restrict__ cf, int tid)
{
  const int L  = tid & 63;
  const int w  = tid >> 6;
  const int mt = w & 1;
  const int pg = w >> 1;   // 0..3

  bf16x8 Af[4][4];
  {
    const short* wb = wf + (mt*32 + (L & 31))*64 + ((L >> 5) << 3);
    #pragma unroll
    for (int pd = 0; pd < 4; ++pd)
      #pragma unroll
      for (int ks = 0; ks < 4; ++ks)
        Af[pd][ks] = *(const bf16x8*)(wb + pd*4096 + ks*16);
  }
  f32x16 binit;
  #pragma unroll
  for (int r = 0; r < 16; ++r)
    binit[r] = bias[mt*32 + (r & 3) + 8*(r >> 2) + 4*(L >> 5)];

  for (int n = pg; n < 8; n += 4) {
    int sl = n*32 + (L & 31);                       // pair local, 0..255
    const short* bp = bin + (sl + 1)*72 + ((L >> 5) << 3);
    f32x16 Ce = binit, Co = binit;
    #pragma unroll
    for (int ks = 0; ks < 4; ++ks) {
      bf16x8 Bm = *(const bf16x8*)(bp + ks*16);
      bf16x8 B0 = *(const bf16x8*)(bp + 72 + ks*16);
      bf16x8 Bp = *(const bf16x8*)(bp + 144 + ks*16);
      Ce = __builtin_amdgcn_mfma_f32_32x32x16_bf16(Af[0][ks], Bm, Ce, 0, 0, 0);
      Ce = __builtin_amdgcn_mfma_f32_32x32x16_bf16(Af[1][ks], B0, Ce, 0, 0, 0);
      Co = __builtin_amdgcn_mfma_f32_32x32x16_bf16(Af[2][ks], B0, Co, 0, 0, 0);
      Co = __builtin_amdgcn_mfma_f32_32x32x16_bf16(Af[3][ks], Bp, Co, 0, 0, 0);
    }
    float c0e = 0.f, c1e = 0.f, c2e = 0.f;
    float c0o = 0.f, c1o = 0.f, c2o = 0.f;
    #pragma unroll
    for (int r = 0; r < 16; ++r) {
      int ch = mt*32 + 8*(r >> 2) + 4*(L >> 5) + (r & 3);
      float4 w4 = *(const float4*)&wl4[ch*4];
      float ye = lrelu(Ce[r]);
      float yo = lrelu(Co[r]);
      c0e = fmaf(w4.x, ye, c0e); c1e = fmaf(w4.y, ye, c1e); c2e = fmaf(w4.z, ye, c2e);
      c0o = fmaf(w4.x, yo, c0o); c1o = fmaf(w4.y, yo, c1o); c2o = fmaf(w4.z, yo, c2o);
    }
    c0e += __shfl_xor(c0e, 32, 64); c1e += __shfl_xor(c1e, 32, 64);
    c2e += __shfl_xor(c2e, 32, 64); c0o += __shfl_xor(c0o, 32, 64);
    c1o += __shfl_xor(c1o, 32, 64); c2o += __shfl_xor(c2o, 32, 64);
    if (L < 32) {
      int fe = 2*sl, fo = fe + 1;                   // local frame 0..511
      cf[mt*1536 + fe]        = c0e; cf[mt*1536 + 512 + fe]  = c1e;
      cf[mt*1536 + 1024 + fe] = c2e;
      cf[mt*1536 + fo]        = c0o; cf[mt*1536 + 512 + fo]  = c1o;
      cf[mt*1536 + 1024 + fo] = c2o;
    }
  }
}

// ---------------------------------------------------------------------------
// up345 v4: noise layers 0..6 + coeff projection fused (y0 T=32 -> squared
// rfft coeffs), all in LDS, 512 threads (8 waves = 4 wave-pairs) for latency
// hiding. NO min-occupancy launch bound (round-9 lesson: (512,4) forced a
// 64-VGPR spill; compiler needs ~128 for these stages). Block (bx, b),
// bx in [0,8): frames [512bx, 512bx+512). Halo chain identical to r8.
// ---------------------------------------------------------------------------
__global__ __launch_bounds__(512) void up345(
    const unsigned short* __restrict__ y0g,
    const short* __restrict__ wfold, const float* __restrict__ nzu_b,
    const float* __restrict__ nzf_w, const float* __restrict__ nzf_b,
    float* __restrict__ csq)            // [3][64*4096] squared coeffs
{
  // rows: y0b 34 | y1b 35 | y2b 66 | s3 66 | s4 128 | s5 192  (x72 shorts)
  __shared__ __align__(16) short arena[521 * 72];   // 75024 B
  __shared__ float wl4[256];                        // [c]{w0,w1,w2,0}
  short* y0b = arena;                //  34 rows
  short* y1b = arena + 34*72;        //  35 rows
  short* y2b = arena + 69*72;        //  66 rows
  short* s3  = arena + 135*72;       //  66 rows
  short* s4  = arena + 201*72;       // 128 rows
  short* s5  = arena + 329*72;       // 192 rows
  short* s6  = arena;                // 260 rows, overlays y0b..s4 (phase 2)
  float* cf  = (float*)(arena + 329*72);  // 3072 f32, overlays s5 (phase 3)

  const int b   = blockIdx.y;
  const int bx  = blockIdx.x;    // 0..7
  const int tid = threadIdx.x;

  if (tid < 64) {
    wl4[tid*4 + 0] = nzf_w[tid];
    wl4[tid*4 + 1] = nzf_w[64 + tid];
    wl4[tid*4 + 2] = nzf_w[128 + tid];
    wl4[tid*4 + 3] = 0.f;
  }
  // zero-init arena (4689 uint4)
  for (int i = tid; i < 4689; i += 512) ((uint4*)arena)[i] = make_uint4(0,0,0,0);
  __syncthreads();

  // stage y0 tile: row r <- sample 4bx-2+r (only valid samples loaded)
  const unsigned short* inb = y0g + (size_t)b * 32 * 64;
  for (int c = tid; c < 34*8; c += 512) {
    int row = c >> 3, pos = (c & 7) << 3;
    int g = 4*bx - 2 + row;
    if (g >= 0 && g < 32)
      *(bf16x8*)&y0b[row*72 + pos] = *(const bf16x8*)(inb + (size_t)g*64 + pos);
  }
  __syncthreads();

  int lo, hi;
  lo = 8*bx - 2;   hi = 8*bx + 18;
  up_stage2<1>(y0b, y1b, wfold + 0*16384, nzu_b + 0*64, tid,
               0, 4*bx - 1, lo < 0 ? 0 : lo, hi > 64 ? 64 : hi);
  __syncthreads();
  lo = 16*bx - 2;  hi = 16*bx + 33;
  up_stage2<1>(y1b, y2b, wfold + 1*16384, nzu_b + 1*64, tid,
               0, 8*bx - 1, lo < 0 ? 0 : lo, hi > 128 ? 128 : hi);
  __syncthreads();
  lo = 32*bx - 2;  hi = 32*bx + 64;
  up_stage2<2>(y2b, s3, wfold + 2*16384, nzu_b + 2*64, tid,
               0, 16*bx - 1, lo < 0 ? 0 : lo, hi > 256 ? 256 : hi);
  __syncthreads();
  lo = 64*bx - 2;  hi = 64*bx + 126;
  up_stage2<2>(s3, s4, wfold + 3*16384, nzu_b + 3*64, tid,
               0, 32*bx - 1, lo < 0 ? 0 : lo, hi > 512 ? 512 : hi);
  __syncthreads();
  lo = 128*bx - 2; hi = 128*bx + 190;
  up_stage2<3>(s4, s5, wfold + 4*16384, nzu_b + 4*64, tid,
               0, 64*bx - 1, lo < 0 ? 0 : lo, hi > 1024 ? 1024 : hi);
  __syncthreads();

  // re-zero s6 region (260 rows overlay dead y0b..s4) while s5 holds y5
  for (int i = tid; i < 2340; i += 512) ((uint4*)arena)[i] = make_uint4(0,0,0,0);
  __syncthreads();

  // layer 5 -> s6: pairs [128bx-1, 128bx+129), y6 samples [256bx-2,256bx+258)
  hi = 256*bx + 258;
  up_stage2<5>(s5, s6, wfold + 5*16384, nzu_b + 5*64, tid,
               0, 128*bx - 1, 0, hi > 2048 ? 2048 : hi);
  __syncthreads();

  // layer 6 + coeff projection -> cf (overlays dead s5)
  up_stage_coef(s6, wfold + 6*16384, nzu_b + 6*64, wl4, cf, tid);
  __syncthreads();

  // write squared coeffs (3 planes, coalesced): frame fb = 512bx + i
  {
    float b0 = nzf_b[0], b1 = nzf_b[1], b2 = nzf_b[2];
    for (int i = tid; i < 512; i += 512) {
      float c0 = b0 + cf[i]        + cf[1536 + i];
      float c1 = b1 + cf[512 + i]  + cf[1536 + 512 + i];
      float c2 = b2 + cf[1024 + i] + cf[1536 + 1024 + i];
      size_t base = (size_t)b*4096 + 512*bx + i;
      csq[base]            = c0 * c0;
      csq[262144 + base]   = c1 * c1;
      csq[524288 + base]   = c2 * c2;
    }
  }
}

// ---------------------------------------------------------------------------
// Conv-stack helpers: 8-ci chunk register double-buffer for weights (global,
// VMEM pipe) AND z rows (LDS). All indices compile-time after inlining.
// ---------------------------------------------------------------------------
__device__ __forceinline__ void load_w8(float4* W, const float4* wp, int cc) {
  #pragma unroll
  for (int k = 0; k < 8; ++k) W[k] = wp[(cc*8 + k)*64];
}
__device__ __forceinline__ void load_z8(float* Z, const float* pa, int cc, int t0) {
  #pragma unroll
  for (int k = 0; k < 8; ++k) {
    const float* r = pa + (cc*8 + k)*36 + t0;
    float4 a = *(const float4*)r;
    float2 b2 = *(const float2*)(r + 4);
    Z[k*6+0] = a.x; Z[k*6+1] = a.y; Z[k*6+2] = a.z;
    Z[k*6+3] = a.w; Z[k*6+4] = b2.x; Z[k*6+5] = b2.y;
  }
}
__device__ __forceinline__ void fma8(float* acc, const float4* W, const float* Z) {
  #pragma unroll
  for (int k = 0; k < 8; ++k) {
    #pragma unroll
    for (int j = 0; j < 4; ++j) {
      acc[j] = fmaf(W[k].x, Z[k*6+j],   acc[j]);
      acc[j] = fmaf(W[k].y, Z[k*6+j+1], acc[j]);
      acc[j] = fmaf(W[k].z, Z[k*6+j+2], acc[j]);
    }
  }
}

// ---------------------------------------------------------------------------
// z_front v3: 512 threads/block, one block per batch. Conv stack only (plus
// y0 / amp / freq / fp64-phase). Noise layers live in up345.
// ---------------------------------------------------------------------------
__global__ __launch_bounds__(512, 2) void z_front(
    const float* __restrict__ x, const float* __restrict__ wtF4,
    const float* __restrict__ net_b, const float* __restrict__ fin_b,
    const float* __restrict__ awfwT, const float* __restrict__ amp_b,
    const float* __restrict__ frq_b,
    const float* __restrict__ nzT, const float* __restrict__ nzi_b,
    unsigned short* __restrict__ y0g, float* __restrict__ amp_o,
    float* __restrict__ frq_o, float* __restrict__ ph_o)
{
  // arena (31104 B): za [0,9216) | zb [9216,18432) | zt [18432,26880)
  //                  fl [26880,31104)
  __shared__ __align__(16) char arena[31104];
  float* za = (float*)arena;
  float* zb = (float*)(arena + 9216);
  float* zt = (float*)(arena + 18432);
  float* fl = (float*)(arena + 26880);

  const int b   = blockIdx.x;
  const int tid = threadIdx.x;
  const int co  = tid & 63;
  const int wv  = tid >> 6;   // 0..7

  // stage input (rows shifted +1: za[c][s] = x[c][s-1]); zero halos
  for (int idx = tid; idx < 2048; idx += 512) {
    int t = idx >> 6, c = idx & 63;
    za[c*36 + t + 1] = x[b*2048 + idx];
  }
  if (tid < 64) {
    za[tid*36] = 0.f; za[tid*36 + 33] = 0.f;
    zb[tid*36] = 0.f; zb[tid*36 + 33] = 0.f;
  }
  __syncthreads();

  // ---- conv stack: 8 waves, 4 t/thread, dual (w,z) 8-ci double-buffer ----
  float* pa = za;
  float* pb = zb;
  for (int l = 0; l < 5; ++l) {
    {
      const int t0 = wv << 2;
      float bv = (l < 4) ? net_b[l*64 + co] : fin_b[co];
      float acc[4];
      #pragma unroll
      for (int j = 0; j < 4; ++j) acc[j] = bv;

      const float4* wp = ((const float4*)wtF4) + l*4096 + co;  // [ci*64]
      float4 wA[8], wB[8];
      float  zA[48], zB[48];
      load_w8(wA, wp, 0);
      load_z8(zA, pa, 0, t0);

      #pragma unroll
      for (int cc = 0; cc < 8; ++cc) {
        if (cc & 1) {
          if (cc < 7) { load_w8(wA, wp, cc + 1); load_z8(zA, pa, cc + 1, t0); }
          fma8(acc, wB, zB);
        } else {
          if (cc < 7) { load_w8(wB, wp, cc + 1); load_z8(zB, pa, cc + 1, t0); }
          fma8(acc, wA, zA);
        }
      }

      if (l < 4) {
        #pragma unroll
        for (int j = 0; j < 4; ++j)
          pb[co*36 + t0 + j + 1] = lrelu(acc[j]);
      } else {
        // final z: store UNSHIFTED (cols 0..31) + transposed copy for proj
        #pragma unroll
        for (int j = 0; j < 4; ++j) {
          int t = t0 + j;
          pb[co*36 + t] = acc[j];
          zt[t*66 + co] = acc[j];
        }
      }
    }
    __syncthreads();
    float* tp = pa; pa = pb; pb = tp;
  }
  const float* zf = pa;  // final z, 64ch x 32t, cols 0..31 (no halo shift)

  // ---- y0 = nz_init 1x1 conv -> bf16 -> GLOBAL [b][t][co] ----
  {
    const int q = wv;          // 0..7, t = q*4..q*4+3
    float bv0 = nzi_b[co];
    float acc[4];
    #pragma unroll
    for (int j = 0; j < 4; ++j) acc[j] = bv0;
    #pragma unroll 8
    for (int c = 0; c < 64; ++c) {
      float4 zv = *(const float4*)(zf + c*36 + (q << 2));
      float wvv = nzT[c*64 + co];
      acc[0] = fmaf(wvv, zv.x, acc[0]);
      acc[1] = fmaf(wvv, zv.y, acc[1]);
      acc[2] = fmaf(wvv, zv.z, acc[2]);
      acc[3] = fmaf(wvv, zv.w, acc[3]);
    }
    unsigned short* yb = y0g + (size_t)b * 2048;
    #pragma unroll
    for (int j = 0; j < 4; ++j)
      yb[((q << 2) + j)*64 + co] = f2bf(acc[j]);
  }

  // ---- amp / freq projections: global paired b128 weights + zt b64 reads ---
  #pragma unroll
  for (int tt = 0; tt < 2; ++tt) {
    int task = tid + 512*tt;
    int o = task & 31, t = task >> 5;
    float aa = amp_b[o], ff = frq_b[o];
    #pragma unroll 8
    for (int c2 = 0; c2 < 32; ++c2) {
      float4 w4 = ((const float4*)awfwT)[c2*32 + o];
      float2 zv = *(const float2*)(zt + t*66 + c2*2);
      aa = fmaf(w4.x, zv.x, aa); ff = fmaf(w4.y, zv.x, ff);
      aa = fmaf(w4.z, zv.y, aa); ff = fmaf(w4.w, zv.y, ff);
    }
    aa = fabsf(aa);
    float sg = 1.f / (1.f + expf(-ff));
    float fq = LOWEST_FREQ_F + sg * (1.f - LOWEST_FREQ_F);
    amp_o[b*1024 + o*32 + t] = aa;
    frq_o[b*1024 + o*32 + t] = fq;
    fl[o*33 + t] = fq;
  }
  __syncthreads();

  // ---- fp64 phase boundary prefix on wave 7 ----
  if (wv == 7 && (tid & 63) < 32) {
    const int o = tid & 31;
    double P = 256.0 * (double)fl[o*33];
    double hd = P * 0.5;
    ph_o[b*1024 + o*32] = (float)(hd - floor(hd));
    for (int i = 1; i < 32; ++i) {
      P += 256.0 * ((double)fl[o*33 + i - 1] + (double)fl[o*33 + i]);
      hd = P * 0.5;
      ph_o[b*1024 + o*32 + i] = (float)(hd - floor(hd));
    }
  }
}

// ---------------------------------------------------------------------------
// osc_noise: oscillator bank + length-4 ortho rfft/irfft noise filter.
// One thread per frame; squared coeffs read from global (computed in up345).
// ---------------------------------------------------------------------------
__global__ __launch_bounds__(256) void osc_noise(
    const float* __restrict__ csq,      // [3][64*4096] squared coeffs
    const float* __restrict__ noise,
    const float* __restrict__ amp, const float* __restrict__ frq,
    const float* __restrict__ ph, float* __restrict__ out)
{
  __shared__ float al[1024], fqv[1024], pl[1024];   // 12288 B

  const int b   = blockIdx.y;
  const int tid = threadIdx.x;
  const int fb  = blockIdx.x * 256 + tid;           // frame in [0,4096)

  for (int i = tid; i < 1024; i += 256) {
    al[i]  = amp[b*1024 + i];
    fqv[i] = frq[b*1024 + i];
    pl[i]  = ph[b*1024 + i];
  }
  __syncthreads();

  const size_t base = (size_t)b*4096 + fb;
  float c0 = csq[base];
  float c1 = csq[262144 + base];
  float c2 = csq[524288 + base];

  const float4 n = *(const float4*)(noise + base*4);
  float F0  = c0 * (n.x + n.y + n.z + n.w) * 0.5f;
  float F1r = c1 * (n.x - n.z) * 0.5f;
  float F1i = -(c1 * (n.y - n.w) * 0.5f);
  float F2  = c2 * (n.x - n.y + n.z - n.w) * 0.5f;
  float r0 = 0.5f * (F0 + 2.f*F1r + F2);
  float r1 = 0.5f * (F0 - 2.f*F1i - F2);
  float r2 = 0.5f * (F0 - 2.f*F1r + F2);
  float r3 = 0.5f * (F0 + 2.f*F1i - F2);

  const int t0 = fb * 4;
  float s0a = 0.f, s1a = 0.f, s2a = 0.f, s3a = 0.f;
  if (t0 < 256) {                      // head: freq=f0, amp=a0
    const float tp = (float)(t0 + 1) * 0.5f;
    #pragma unroll 4
    for (int o = 0; o < 32; ++o) {
      float f0 = fqv[o*32], am = al[o*32];
      float hf = 0.5f * f0;
      float v0 = tp * f0, v1 = v0 + hf, v2 = v1 + hf, v3 = v2 + hf;
      s0a += am * sin_rev(v0 - floorf(v0));
      s1a += am * sin_rev(v1 - floorf(v1));
      s2a += am * sin_rev(v2 - floorf(v2));
      s3a += am * sin_rev(v3 - floorf(v3));
    }
  } else if (t0 >= 16128) {            // tail: freq=f31, amp=a31
    const float tp = (float)(t0 - 16127) * 0.5f;
    #pragma unroll 4
    for (int o = 0; o < 32; ++o) {
      float f0 = fqv[o*32 + 31], am = al[o*32 + 31], p = pl[o*32 + 31];
      float hf = 0.5f * f0;
      float v0 = p + tp * f0, v1 = v0 + hf, v2 = v1 + hf, v3 = v2 + hf;
      s0a += am * sin_rev(v0 - floorf(v0));
      s1a += am * sin_rev(v1 - floorf(v1));
      s2a += am * sin_rev(v2 - floorf(v2));
      s3a += am * sin_rev(v3 - floorf(v3));
    }
  } else {                             // middle: same interp cell for all 4
    const int i  = (t0 - 256) >> 9;
    const int m0 = (t0 - 256) & 511;
    float mm[4], fa[4], mq[4];
    #pragma unroll
    for (int js = 0; js < 4; ++js) {
      float mmv = (float)(m0 + 1 + js);
      mm[js] = mmv;
      fa[js] = ((float)(m0 + js) + 0.5f) * (1.f/512.f);
      mq[js] = mmv * mmv * (1.f/1024.f);
    }
    #pragma unroll 4
    for (int o = 0; o < 32; ++o) {
      float f0 = fqv[o*32 + i], f1 = fqv[o*32 + i + 1];
      float a0 = al[o*32 + i],  a1 = al[o*32 + i + 1];
      float p  = pl[o*32 + i];
      float df = f1 - f0, da = a1 - a0;
      #pragma unroll
      for (int js = 0; js < 4; ++js) {
        float av   = fmaf(da, fa[js], a0);
        float part = fmaf(df, mq[js], mm[js] * f0);
        float v    = fmaf(part, 0.5f, p);
        float fr   = v - floorf(v);
        float sv   = av * sin_rev(fr);
        if      (js == 0) s0a += sv;
        else if (js == 1) s1a += sv;
        else if (js == 2) s2a += sv;
        else              s3a += sv;
      }
    }
  }
  float4 res = make_float4(s0a + r0, s1a + r1, s2a + r2, s3a + r3);
  *(float4*)(out + base*4) = res;
}

// ---------------------------------------------------------------------------
extern "C" void kernel_launch(void* const* d_in, const int* in_sizes, int n_in,
                              void* d_out, int out_size, void* d_ws, size_t ws_size,
                              hipStream_t stream) {
  (void)in_sizes; (void)n_in; (void)out_size; (void)ws_size;
  const float* x     = (const float*)d_in[0];
  const float* noise = (const float*)d_in[1];
  const float* net_w = (const float*)d_in[2];
  const float* net_b = (const float*)d_in[3];
  const float* fin_w = (const float*)d_in[4];
  const float* fin_b = (const float*)d_in[5];
  const float* amp_w = (const float*)d_in[6];
  const float* amp_b = (const float*)d_in[7];
  const float* frq_w = (const float*)d_in[8];
  const float* frq_b = (const float*)d_in[9];
  const float* nzi_w = (const float*)d_in[10];
  const float* nzi_b = (const float*)d_in[11];
  const float* nzu_w = (const float*)d_in[12];
  const float* nzu_b = (const float*)d_in[13];
  const float* nzf_w = (const float*)d_in[14];
  const float* nzf_b = (const float*)d_in[15];
  float* out = (float*)d_out;

  // workspace (~5 MiB)
  short* y0    = (short*)d_ws;                       // 64*32*64
  short* wfold = y0 + (size_t)64*32*64;              // 7*16384
  float* wtF4  = (float*)(wfold + 7*16384);          // 5*4096*4 = 81920
  float* awfwT = wtF4 + 81920;                       // 4096
  float* nzT   = awfwT + 4096;                       // 4096
  float* ampv  = nzT + 4096;                         // 65536
  float* frqv  = ampv + 65536;                       // 65536
  float* phv   = frqv + 65536;                       // 65536
  float* csq   = phv + 65536;                        // 3*262144

  prep_kernel<<<dim3(13), dim3(256), 0, stream>>>(
      net_w, fin_w, amp_w, frq_w, nzi_w, nzu_w, wtF4, awfwT, nzT, wfold);

  z_front<<<dim3(64), dim3(512), 0, stream>>>(
      x, wtF4, net_b, fin_b, awfwT, amp_b, frq_b, nzT, nzi_b,
      (unsigned short*)y0, ampv, frqv, phv);

  up345<<<dim3(8, 64), dim3(512), 0, stream>>>(
      (unsigned short*)y0, wfold, nzu_b, nzf_w, nzf_b, csq);

  osc_noise<<<dim3(16, 64), dim3(256), 0, stream>>>(
      csq, noise, ampv, frqv, phv, out);
}

// Round 11
// 173.920 us; speedup vs baseline: 1.3370x; 1.1349x over previous
//
#include <hip/hip_runtime.h>
#include <math.h>

// Problem constants
//  B=64, CH=64, T_IN=32, N_OSC=32, BAND=16384, N_NOISE_FRAMES=4096, NOISE_STEP=4
//  N_UP=7, LOWEST_FREQ = 20/11025
#define LOWEST_FREQ_F 0.00181405895691609977f

typedef short bf16x8 __attribute__((ext_vector_type(8)));
typedef float f32x16 __attribute__((ext_vector_type(16)));

__device__ __forceinline__ float lrelu(float x) { return x > 0.f ? x : 0.2f * x; }
__device__ __forceinline__ float sin_rev(float fr) { return __builtin_amdgcn_sinf(fr); }
__device__ __forceinline__ float bf2f(unsigned short u) {
  union { unsigned int i; float f; } x; x.i = ((unsigned int)u) << 16; return x.f;
}
__device__ __forceinline__ unsigned short f2bf(float f) {
  union { float f; unsigned int i; } x; x.f = f;
  unsigned int r = x.i + 0x7FFFu + ((x.i >> 16) & 1u);   // RNE
  return (unsigned short)(r >> 16);
}
__device__ __forceinline__ unsigned int pack2(float a, float b) {
  return (unsigned int)f2bf(a) | ((unsigned int)f2bf(b) << 16);
}

// ---------------------------------------------------------------------------
// prep v2: LDS-staged, coalesced. One block per weight-layer (13 blocks).
// ---------------------------------------------------------------------------
__global__ __launch_bounds__(256) void prep_kernel(
    const float* __restrict__ net_w, const float* __restrict__ fin_w,
    const float* __restrict__ amp_w, const float* __restrict__ frq_w,
    const float* __restrict__ nzi_w, const float* __restrict__ nzu_w,
    float* __restrict__ wtF4, float* __restrict__ awfwT,
    float* __restrict__ nzT, short* __restrict__ wfold)
{
  __shared__ __align__(16) float wls[12288];   // 48 KB
  const int tid = threadIdx.x;
  const int bx  = blockIdx.x;

  if (bx < 7) {                 // ---- wfold layer bx ----
    const float4* src = (const float4*)(nzu_w + bx * 12288);
    #pragma unroll
    for (int i = 0; i < 12; ++i)
      ((float4*)wls)[tid + i*256] = src[tid + i*256];
    __syncthreads();
    short* dst = wfold + bx * 16384;
    for (int i = 0; i < 64; ++i) {
      int q = i*256 + tid;
      int pd = q >> 12, co = (q >> 6) & 63, ci = q & 63;
      const float* wb = wls + co*192 + ci*3;
      float v;
      if      (pd == 0) v = wb[0];
      else if (pd == 1) v = wb[1] + wb[2];
      else if (pd == 2) v = wb[0] + wb[1];
      else              v = wb[2];
      dst[q] = (short)f2bf(v);
    }
  } else if (bx < 12) {         // ---- wtF4 layer l ----
    int l = bx - 7;
    const float* s0 = (l < 4) ? (net_w + l * 12288) : fin_w;
    const float4* src = (const float4*)s0;
    #pragma unroll
    for (int i = 0; i < 12; ++i)
      ((float4*)wls)[tid + i*256] = src[tid + i*256];
    __syncthreads();
    float4* dst = ((float4*)wtF4) + l * 4096;
    for (int i = 0; i < 16; ++i) {
      int q = i*256 + tid;
      int ci = q >> 6, co = q & 63;
      const float* wb = wls + co*192 + ci*3;
      dst[q] = make_float4(wb[0], wb[1], wb[2], 0.f);
    }
  } else {                      // ---- awfwT + nzT ----
    #pragma unroll
    for (int i = 0; i < 2; ++i)
      ((float4*)wls)[tid + i*256] = ((const float4*)amp_w)[tid + i*256];
    #pragma unroll
    for (int i = 0; i < 2; ++i)
      ((float4*)(wls + 2048))[tid + i*256] = ((const float4*)frq_w)[tid + i*256];
    #pragma unroll
    for (int i = 0; i < 4; ++i)
      ((float4*)(wls + 4096))[tid + i*256] = ((const float4*)nzi_w)[tid + i*256];
    __syncthreads();
    for (int i = 0; i < 16; ++i) {
      int q = i*256 + tid;
      int c2 = q >> 7, rem = q & 127, o = rem >> 2, k = rem & 3;
      int c = c2*2 + (k >> 1);
      awfwT[q] = (k & 1) ? wls[2048 + o*64 + c] : wls[o*64 + c];
    }
    for (int i = 0; i < 16; ++i) {
      int q = i*256 + tid;
      int c = q >> 6, o = q & 63;
      nzT[q] = wls[4096 + o*64 + c];
    }
  }
}

// ---------------------------------------------------------------------------
// Generalized in-LDS up-conv stage with halo-exact masked stores.
// 256-thread version (r8-proven optimal): 4 waves = 2 wave-pairs, tile n
// handled by pair (n&1).
// v_mfma_f32_32x32x16_bf16 (HW-verified): A[m=L&31][k=(L>>5)*8+j],
// B[k][n=L&31], D col=L&31, row=(r&3)+8*(r>>2)+4*(L>>5).
// ---------------------------------------------------------------------------
template<int NT>
__device__ __forceinline__ void up_stage2(
    const short* bin, short* bout,
    const short* __restrict__ wf, const float* __restrict__ bias, int tid,
    int roff, int pairbase, int smin, int smax)
{
  const int L  = tid & 63;
  const int w  = tid >> 6;
  const int mt = w & 1;
  const int pg = w >> 1;   // 0..1

  bf16x8 Af[4][4];
  {
    const short* wb = wf + (mt*32 + (L & 31))*64 + ((L >> 5) << 3);
    #pragma unroll
    for (int pd = 0; pd < 4; ++pd)
      #pragma unroll
      for (int ks = 0; ks < 4; ++ks)
        Af[pd][ks] = *(const bf16x8*)(wb + pd*4096 + ks*16);
  }
  f32x16 binit;
  #pragma unroll
  for (int r = 0; r < 16; ++r)
    binit[r] = bias[mt*32 + (r & 3) + 8*(r >> 2) + 4*(L >> 5)];

  for (int n = pg; n < NT; n += 2) {
    int sl = n*32 + (L & 31);
    const short* bp = bin + (sl + roff)*72 + ((L >> 5) << 3);
    f32x16 Ce = binit, Co = binit;
    #pragma unroll
    for (int ks = 0; ks < 4; ++ks) {
      bf16x8 Bm = *(const bf16x8*)(bp + ks*16);
      bf16x8 B0 = *(const bf16x8*)(bp + 72 + ks*16);
      bf16x8 Bp = *(const bf16x8*)(bp + 144 + ks*16);
      Ce = __builtin_amdgcn_mfma_f32_32x32x16_bf16(Af[0][ks], Bm, Ce, 0, 0, 0);
      Ce = __builtin_amdgcn_mfma_f32_32x32x16_bf16(Af[1][ks], B0, Ce, 0, 0, 0);
      Co = __builtin_amdgcn_mfma_f32_32x32x16_bf16(Af[2][ks], B0, Co, 0, 0, 0);
      Co = __builtin_amdgcn_mfma_f32_32x32x16_bf16(Af[3][ks], Bp, Co, 0, 0, 0);
    }
    const int s0 = 2*(sl + pairbase);
    const bool we = (s0 >= smin)     && (s0 < smax);
    const bool wo = (s0 + 1 >= smin) && (s0 + 1 < smax);
    #pragma unroll
    for (int q4 = 0; q4 < 4; ++q4) {
      int co0 = mt*32 + 8*q4 + 4*(L >> 5);
      uint2 ve, vo;
      ve.x = pack2(lrelu(Ce[4*q4+0]), lrelu(Ce[4*q4+1]));
      ve.y = pack2(lrelu(Ce[4*q4+2]), lrelu(Ce[4*q4+3]));
      vo.x = pack2(lrelu(Co[4*q4+0]), lrelu(Co[4*q4+1]));
      vo.y = pack2(lrelu(Co[4*q4+2]), lrelu(Co[4*q4+3]));
      if (we) *(uint2*)&bout[(2*sl)*72 + co0]     = ve;
      if (wo) *(uint2*)&bout[(2*sl + 1)*72 + co0] = vo;
    }
  }
}

// ---------------------------------------------------------------------------
// Layer-6 stage with in-register nz_final coefficient projection (round-7
// verified): per lane, lrelu + 3-weight FMA over its 16 channels,
// shfl_xor(32) adds the complementary channel half (same frames), then 6
// scalar stores into cf[mt][3][512]. 256-thread: pairs take tiles n&1.
// ---------------------------------------------------------------------------
__device__ __forceinline__ void up_stage_coef(
    const short* bin, const short* __restrict__ wf,
    const float* __restrict__ bias, const float* __restrict__ wl4,
    float* __restrict__ cf, int tid)
{
  const int L  = tid & 63;
  const int w  = tid >> 6;
  const int mt = w & 1;
  const int pg = w >> 1;   // 0..1

  bf16x8 Af[4][4];
  {
    const short* wb = wf + (mt*32 + (L & 31))*64 + ((L >> 5) << 3);
    #pragma unroll
    for (int pd = 0; pd < 4; ++pd)
      #pragma unroll
      for (int ks = 0; ks < 4; ++ks)
        Af[pd][ks] = *(const bf16x8*)(wb + pd*4096 + ks*16);
  }
  f32x16 binit;
  #pragma unroll
  for (int r = 0; r < 16; ++r)
    binit[r] = bias[mt*32 + (r & 3) + 8*(r >> 2) + 4*(L >> 5)];

  for (int n = pg; n < 8; n += 2) {
    int sl = n*32 + (L & 31);                       // pair local, 0..255
    const short* bp = bin + (sl + 1)*72 + ((L >> 5) << 3);
    f32x16 Ce = binit, Co = binit;
    #pragma unroll
    for (int ks = 0; ks < 4; ++ks) {
      bf16x8 Bm = *(const bf16x8*)(bp + ks*16);
      bf16x8 B0 = *(const bf16x8*)(bp + 72 + ks*16);
      bf16x8 Bp = *(const bf16x8*)(bp + 144 + ks*16);
      Ce = __builtin_amdgcn_mfma_f32_32x32x16_bf16(Af[0][ks], Bm, Ce, 0, 0, 0);
      Ce = __builtin_amdgcn_mfma_f32_32x32x16_bf16(Af[1][ks], B0, Ce, 0, 0, 0);
      Co = __builtin_amdgcn_mfma_f32_32x32x16_bf16(Af[2][ks], B0, Co, 0, 0, 0);
      Co = __builtin_amdgcn_mfma_f32_32x32x16_bf16(Af[3][ks], Bp, Co, 0, 0, 0);
    }
    float c0e = 0.f, c1e = 0.f, c2e = 0.f;
    float c0o = 0.f, c1o = 0.f, c2o = 0.f;
    #pragma unroll
    for (int r = 0; r < 16; ++r) {
      int ch = mt*32 + 8*(r >> 2) + 4*(L >> 5) + (r & 3);
      float4 w4 = *(const float4*)&wl4[ch*4];
      float ye = lrelu(Ce[r]);
      float yo = lrelu(Co[r]);
      c0e = fmaf(w4.x, ye, c0e); c1e = fmaf(w4.y, ye, c1e); c2e = fmaf(w4.z, ye, c2e);
      c0o = fmaf(w4.x, yo, c0o); c1o = fmaf(w4.y, yo, c1o); c2o = fmaf(w4.z, yo, c2o);
    }
    c0e += __shfl_xor(c0e, 32, 64); c1e += __shfl_xor(c1e, 32, 64);
    c2e += __shfl_xor(c2e, 32, 64); c0o += __shfl_xor(c0o, 32, 64);
    c1o += __shfl_xor(c1o, 32, 64); c2o += __shfl_xor(c2o, 32, 64);
    if (L < 32) {
      int fe = 2*sl, fo = fe + 1;                   // local frame 0..511
      cf[mt*1536 + fe]        = c0e; cf[mt*1536 + 512 + fe]  = c1e;
      cf[mt*1536 + 1024 + fe] = c2e;
      cf[mt*1536 + fo]        = c0o; cf[mt*1536 + 512 + fo]  = c1o;
      cf[mt*1536 + 1024 + fo] = c2o;
    }
  }
}

// ---------------------------------------------------------------------------
// up_osc: noise layers 0..6 + coeff projection + noise filter + oscillator
// bank fused (y0 T=32 -> out), 256 threads (r8/r10-proven optimal wave count
// for the stage chain; r9's spill came from the (512,4) bound, NOT fusion --
// r7's final_fused proved MFMA+osc at 256 threads compiles to 160 VGPR clean).
// Block (bx, b), bx in [0,8): frames [512bx, 512bx+512), 2 frames/thread.
// Halo chain identical to r8. al/fqv/pl overlay dead s6 after coef.
// ---------------------------------------------------------------------------
__global__ __launch_bounds__(256) void up_osc(
    const unsigned short* __restrict__ y0g,
    const short* __restrict__ wfold, const float* __restrict__ nzu_b,
    const float* __restrict__ nzf_w, const float* __restrict__ nzf_b,
    const float* __restrict__ noise,
    const float* __restrict__ amp, const float* __restrict__ frq,
    const float* __restrict__ ph, float* __restrict__ out)
{
  // rows: y0b 34 | y1b 35 | y2b 66 | s3 66 | s4 128 | s5 192  (x72 shorts)
  __shared__ __align__(16) short arena[521 * 72];   // 75024 B
  __shared__ float wl4[256];                        // [c]{w0,w1,w2,0}
  short* y0b = arena;                //  34 rows
  short* y1b = arena + 34*72;        //  35 rows
  short* y2b = arena + 69*72;        //  66 rows
  short* s3  = arena + 135*72;       //  66 rows
  short* s4  = arena + 201*72;       // 128 rows
  short* s5  = arena + 329*72;       // 192 rows
  short* s6  = arena;                // 260 rows, overlays y0b..s4 (phase 2)
  float* cf  = (float*)(arena + 329*72);  // 3072 f32, overlays s5 (phase 3)
  float* al  = (float*)arena;             // 1024 f32, overlays s6 (phase 4)
  float* fqv = (float*)arena + 1024;
  float* pl  = (float*)arena + 2048;

  const int b   = blockIdx.y;
  const int bx  = blockIdx.x;    // 0..7
  const int tid = threadIdx.x;

  if (tid < 64) {
    wl4[tid*4 + 0] = nzf_w[tid];
    wl4[tid*4 + 1] = nzf_w[64 + tid];
    wl4[tid*4 + 2] = nzf_w[128 + tid];
    wl4[tid*4 + 3] = 0.f;
  }
  // zero-init arena (4689 uint4)
  for (int i = tid; i < 4689; i += 256) ((uint4*)arena)[i] = make_uint4(0,0,0,0);
  __syncthreads();

  // stage y0 tile: row r <- sample 4bx-2+r (only valid samples loaded)
  const unsigned short* inb = y0g + (size_t)b * 32 * 64;
  for (int c = tid; c < 34*8; c += 256) {
    int row = c >> 3, pos = (c & 7) << 3;
    int g = 4*bx - 2 + row;
    if (g >= 0 && g < 32)
      *(bf16x8*)&y0b[row*72 + pos] = *(const bf16x8*)(inb + (size_t)g*64 + pos);
  }
  __syncthreads();

  int lo, hi;
  lo = 8*bx - 2;   hi = 8*bx + 18;
  up_stage2<1>(y0b, y1b, wfold + 0*16384, nzu_b + 0*64, tid,
               0, 4*bx - 1, lo < 0 ? 0 : lo, hi > 64 ? 64 : hi);
  __syncthreads();
  lo = 16*bx - 2;  hi = 16*bx + 33;
  up_stage2<1>(y1b, y2b, wfold + 1*16384, nzu_b + 1*64, tid,
               0, 8*bx - 1, lo < 0 ? 0 : lo, hi > 128 ? 128 : hi);
  __syncthreads();
  lo = 32*bx - 2;  hi = 32*bx + 64;
  up_stage2<2>(y2b, s3, wfold + 2*16384, nzu_b + 2*64, tid,
               0, 16*bx - 1, lo < 0 ? 0 : lo, hi > 256 ? 256 : hi);
  __syncthreads();
  lo = 64*bx - 2;  hi = 64*bx + 126;
  up_stage2<2>(s3, s4, wfold + 3*16384, nzu_b + 3*64, tid,
               0, 32*bx - 1, lo < 0 ? 0 : lo, hi > 512 ? 512 : hi);
  __syncthreads();
  lo = 128*bx - 2; hi = 128*bx + 190;
  up_stage2<3>(s4, s5, wfold + 4*16384, nzu_b + 4*64, tid,
               0, 64*bx - 1, lo < 0 ? 0 : lo, hi > 1024 ? 1024 : hi);
  __syncthreads();

  // re-zero s6 region (260 rows overlay dead y0b..s4) while s5 holds y5
  for (int i = tid; i < 2340; i += 256) ((uint4*)arena)[i] = make_uint4(0,0,0,0);
  __syncthreads();

  // layer 5 -> s6: pairs [128bx-1, 128bx+129), y6 samples [256bx-2,256bx+258)
  hi = 256*bx + 258;
  up_stage2<5>(s5, s6, wfold + 5*16384, nzu_b + 5*64, tid,
               0, 128*bx - 1, 0, hi > 2048 ? 2048 : hi);
  __syncthreads();

  // layer 6 + coeff projection -> cf (overlays dead s5)
  up_stage_coef(s6, wfold + 6*16384, nzu_b + 6*64, wl4, cf, tid);
  __syncthreads();

  // stage amp/frq/ph into the dead s6 overlay
  for (int i = tid; i < 1024; i += 256) {
    al[i]  = amp[b*1024 + i];
    fqv[i] = frq[b*1024 + i];
    pl[i]  = ph[b*1024 + i];
  }
  __syncthreads();

  // ---- epilogue: 2 frames per thread (local frames tid, tid+256) ----
  for (int fi = 0; fi < 2; ++fi) {
    const int lf = tid + fi*256;               // local frame 0..511
    float c0 = nzf_b[0] + cf[lf]        + cf[1536 + lf];
    float c1 = nzf_b[1] + cf[512 + lf]  + cf[1536 + 512 + lf];
    float c2 = nzf_b[2] + cf[1024 + lf] + cf[1536 + 1024 + lf];
    c0 *= c0; c1 *= c1; c2 *= c2;

    const int fb = 512*bx + lf;                // frame in [0,4096)
    const size_t base = (size_t)b*4096 + fb;
    const float4 n = *(const float4*)(noise + base*4);
    float F0  = c0 * (n.x + n.y + n.z + n.w) * 0.5f;
    float F1r = c1 * (n.x - n.z) * 0.5f;
    float F1i = -(c1 * (n.y - n.w) * 0.5f);
    float F2  = c2 * (n.x - n.y + n.z - n.w) * 0.5f;
    float r0 = 0.5f * (F0 + 2.f*F1r + F2);
    float r1 = 0.5f * (F0 - 2.f*F1i - F2);
    float r2 = 0.5f * (F0 - 2.f*F1r + F2);
    float r3 = 0.5f * (F0 + 2.f*F1i - F2);

    const int t0 = fb * 4;
    float s0a = 0.f, s1a = 0.f, s2a = 0.f, s3a = 0.f;
    if (t0 < 256) {                      // head: freq=f0, amp=a0
      const float tp = (float)(t0 + 1) * 0.5f;
      #pragma unroll 4
      for (int o = 0; o < 32; ++o) {
        float f0 = fqv[o*32], am = al[o*32];
        float hf = 0.5f * f0;
        float v0 = tp * f0, v1 = v0 + hf, v2 = v1 + hf, v3 = v2 + hf;
        s0a += am * sin_rev(v0 - floorf(v0));
        s1a += am * sin_rev(v1 - floorf(v1));
        s2a += am * sin_rev(v2 - floorf(v2));
        s3a += am * sin_rev(v3 - floorf(v3));
      }
    } else if (t0 >= 16128) {            // tail: freq=f31, amp=a31
      const float tp = (float)(t0 - 16127) * 0.5f;
      #pragma unroll 4
      for (int o = 0; o < 32; ++o) {
        float f0 = fqv[o*32 + 31], am = al[o*32 + 31], p = pl[o*32 + 31];
        float hf = 0.5f * f0;
        float v0 = p + tp * f0, v1 = v0 + hf, v2 = v1 + hf, v3 = v2 + hf;
        s0a += am * sin_rev(v0 - floorf(v0));
        s1a += am * sin_rev(v1 - floorf(v1));
        s2a += am * sin_rev(v2 - floorf(v2));
        s3a += am * sin_rev(v3 - floorf(v3));
      }
    } else {                             // middle: same interp cell for all 4
      const int i  = (t0 - 256) >> 9;
      const int m0 = (t0 - 256) & 511;
      float mm[4], fa[4], mq[4];
      #pragma unroll
      for (int js = 0; js < 4; ++js) {
        float mmv = (float)(m0 + 1 + js);
        mm[js] = mmv;
        fa[js] = ((float)(m0 + js) + 0.5f) * (1.f/512.f);
        mq[js] = mmv * mmv * (1.f/1024.f);
      }
      #pragma unroll 4
      for (int o = 0; o < 32; ++o) {
        float f0 = fqv[o*32 + i], f1 = fqv[o*32 + i + 1];
        float a0 = al[o*32 + i],  a1 = al[o*32 + i + 1];
        float p  = pl[o*32 + i];
        float df = f1 - f0, da = a1 - a0;
        #pragma unroll
        for (int js = 0; js < 4; ++js) {
          float av   = fmaf(da, fa[js], a0);
          float part = fmaf(df, mq[js], mm[js] * f0);
          float v    = fmaf(part, 0.5f, p);
          float fr   = v - floorf(v);
          float sv   = av * sin_rev(fr);
          if      (js == 0) s0a += sv;
          else if (js == 1) s1a += sv;
          else if (js == 2) s2a += sv;
          else              s3a += sv;
        }
      }
    }
    float4 res = make_float4(s0a + r0, s1a + r1, s2a + r2, s3a + r3);
    *(float4*)(out + base*4) = res;
  }
}

// ---------------------------------------------------------------------------
// Conv-stack helpers: 8-ci chunk register double-buffer for weights (global,
// VMEM pipe) AND z rows (LDS). All indices compile-time after inlining.
// ---------------------------------------------------------------------------
__device__ __forceinline__ void load_w8(float4* W, const float4* wp, int cc) {
  #pragma unroll
  for (int k = 0; k < 8; ++k) W[k] = wp[(cc*8 + k)*64];
}
__device__ __forceinline__ void load_z8(float* Z, const float* pa, int cc, int t0) {
  #pragma unroll
  for (int k = 0; k < 8; ++k) {
    const float* r = pa + (cc*8 + k)*36 + t0;
    float4 a = *(const float4*)r;
    float2 b2 = *(const float2*)(r + 4);
    Z[k*6+0] = a.x; Z[k*6+1] = a.y; Z[k*6+2] = a.z;
    Z[k*6+3] = a.w; Z[k*6+4] = b2.x; Z[k*6+5] = b2.y;
  }
}
__device__ __forceinline__ void fma8(float* acc, const float4* W, const float* Z) {
  #pragma unroll
  for (int k = 0; k < 8; ++k) {
    #pragma unroll
    for (int j = 0; j < 4; ++j) {
      acc[j] = fmaf(W[k].x, Z[k*6+j],   acc[j]);
      acc[j] = fmaf(W[k].y, Z[k*6+j+1], acc[j]);
      acc[j] = fmaf(W[k].z, Z[k*6+j+2], acc[j]);
    }
  }
}

// ---------------------------------------------------------------------------
// z_front v3: 512 threads/block, one block per batch. Conv stack only (plus
// y0 / amp / freq / fp64-phase). Noise layers live in up_osc.
// ---------------------------------------------------------------------------
__global__ __launch_bounds__(512, 2) void z_front(
    const float* __restrict__ x, const float* __restrict__ wtF4,
    const float* __restrict__ net_b, const float* __restrict__ fin_b,
    const float* __restrict__ awfwT, const float* __restrict__ amp_b,
    const float* __restrict__ frq_b,
    const float* __restrict__ nzT, const float* __restrict__ nzi_b,
    unsigned short* __restrict__ y0g, float* __restrict__ amp_o,
    float* __restrict__ frq_o, float* __restrict__ ph_o)
{
  // arena (31104 B): za [0,9216) | zb [9216,18432) | zt [18432,26880)
  //                  fl [26880,31104)
  __shared__ __align__(16) char arena[31104];
  float* za = (float*)arena;
  float* zb = (float*)(arena + 9216);
  float* zt = (float*)(arena + 18432);
  float* fl = (float*)(arena + 26880);

  const int b   = blockIdx.x;
  const int tid = threadIdx.x;
  const int co  = tid & 63;
  const int wv  = tid >> 6;   // 0..7

  // stage input (rows shifted +1: za[c][s] = x[c][s-1]); zero halos
  for (int idx = tid; idx < 2048; idx += 512) {
    int t = idx >> 6, c = idx & 63;
    za[c*36 + t + 1] = x[b*2048 + idx];
  }
  if (tid < 64) {
    za[tid*36] = 0.f; za[tid*36 + 33] = 0.f;
    zb[tid*36] = 0.f; zb[tid*36 + 33] = 0.f;
  }
  __syncthreads();

  // ---- conv stack: 8 waves, 4 t/thread, dual (w,z) 8-ci double-buffer ----
  float* pa = za;
  float* pb = zb;
  for (int l = 0; l < 5; ++l) {
    {
      const int t0 = wv << 2;
      float bv = (l < 4) ? net_b[l*64 + co] : fin_b[co];
      float acc[4];
      #pragma unroll
      for (int j = 0; j < 4; ++j) acc[j] = bv;

      const float4* wp = ((const float4*)wtF4) + l*4096 + co;  // [ci*64]
      float4 wA[8], wB[8];
      float  zA[48], zB[48];
      load_w8(wA, wp, 0);
      load_z8(zA, pa, 0, t0);

      #pragma unroll
      for (int cc = 0; cc < 8; ++cc) {
        if (cc & 1) {
          if (cc < 7) { load_w8(wA, wp, cc + 1); load_z8(zA, pa, cc + 1, t0); }
          fma8(acc, wB, zB);
        } else {
          if (cc < 7) { load_w8(wB, wp, cc + 1); load_z8(zB, pa, cc + 1, t0); }
          fma8(acc, wA, zA);
        }
      }

      if (l < 4) {
        #pragma unroll
        for (int j = 0; j < 4; ++j)
          pb[co*36 + t0 + j + 1] = lrelu(acc[j]);
      } else {
        // final z: store UNSHIFTED (cols 0..31) + transposed copy for proj
        #pragma unroll
        for (int j = 0; j < 4; ++j) {
          int t = t0 + j;
          pb[co*36 + t] = acc[j];
          zt[t*66 + co] = acc[j];
        }
      }
    }
    __syncthreads();
    float* tp = pa; pa = pb; pb = tp;
  }
  const float* zf = pa;  // final z, 64ch x 32t, cols 0..31 (no halo shift)

  // ---- y0 = nz_init 1x1 conv -> bf16 -> GLOBAL [b][t][co] ----
  {
    const int q = wv;          // 0..7, t = q*4..q*4+3
    float bv0 = nzi_b[co];
    float acc[4];
    #pragma unroll
    for (int j = 0; j < 4; ++j) acc[j] = bv0;
    #pragma unroll 8
    for (int c = 0; c < 64; ++c) {
      float4 zv = *(const float4*)(zf + c*36 + (q << 2));
      float wvv = nzT[c*64 + co];
      acc[0] = fmaf(wvv, zv.x, acc[0]);
      acc[1] = fmaf(wvv, zv.y, acc[1]);
      acc[2] = fmaf(wvv, zv.z, acc[2]);
      acc[3] = fmaf(wvv, zv.w, acc[3]);
    }
    unsigned short* yb = y0g + (size_t)b * 2048;
    #pragma unroll
    for (int j = 0; j < 4; ++j)
      yb[((q << 2) + j)*64 + co] = f2bf(acc[j]);
  }

  // ---- amp / freq projections: global paired b128 weights + zt b64 reads ---
  #pragma unroll
  for (int tt = 0; tt < 2; ++tt) {
    int task = tid + 512*tt;
    int o = task & 31, t = task >> 5;
    float aa = amp_b[o], ff = frq_b[o];
    #pragma unroll 8
    for (int c2 = 0; c2 < 32; ++c2) {
      float4 w4 = ((const float4*)awfwT)[c2*32 + o];
      float2 zv = *(const float2*)(zt + t*66 + c2*2);
      aa = fmaf(w4.x, zv.x, aa); ff = fmaf(w4.y, zv.x, ff);
      aa = fmaf(w4.z, zv.y, aa); ff = fmaf(w4.w, zv.y, ff);
    }
    aa = fabsf(aa);
    float sg = 1.f / (1.f + expf(-ff));
    float fq = LOWEST_FREQ_F + sg * (1.f - LOWEST_FREQ_F);
    amp_o[b*1024 + o*32 + t] = aa;
    frq_o[b*1024 + o*32 + t] = fq;
    fl[o*33 + t] = fq;
  }
  __syncthreads();

  // ---- fp64 phase boundary prefix on wave 7 ----
  if (wv == 7 && (tid & 63) < 32) {
    const int o = tid & 31;
    double P = 256.0 * (double)fl[o*33];
    double hd = P * 0.5;
    ph_o[b*1024 + o*32] = (float)(hd - floor(hd));
    for (int i = 1; i < 32; ++i) {
      P += 256.0 * ((double)fl[o*33 + i - 1] + (double)fl[o*33 + i]);
      hd = P * 0.5;
      ph_o[b*1024 + o*32 + i] = (float)(hd - floor(hd));
    }
  }
}

// ---------------------------------------------------------------------------
extern "C" void kernel_launch(void* const* d_in, const int* in_sizes, int n_in,
                              void* d_out, int out_size, void* d_ws, size_t ws_size,
                              hipStream_t stream) {
  (void)in_sizes; (void)n_in; (void)out_size; (void)ws_size;
  const float* x     = (const float*)d_in[0];
  const float* noise = (const float*)d_in[1];
  const float* net_w = (const float*)d_in[2];
  const float* net_b = (const float*)d_in[3];
  const float* fin_w = (const float*)d_in[4];
  const float* fin_b = (const float*)d_in[5];
  const float* amp_w = (const float*)d_in[6];
  const float* amp_b = (const float*)d_in[7];
  const float* frq_w = (const float*)d_in[8];
  const float* frq_b = (const float*)d_in[9];
  const float* nzi_w = (const float*)d_in[10];
  const float* nzi_b = (const float*)d_in[11];
  const float* nzu_w = (const float*)d_in[12];
  const float* nzu_b = (const float*)d_in[13];
  const float* nzf_w = (const float*)d_in[14];
  const float* nzf_b = (const float*)d_in[15];
  float* out = (float*)d_out;

  // workspace (~2 MiB)
  short* y0    = (short*)d_ws;                       // 64*32*64
  short* wfold = y0 + (size_t)64*32*64;              // 7*16384
  float* wtF4  = (float*)(wfold + 7*16384);          // 5*4096*4 = 81920
  float* awfwT = wtF4 + 81920;                       // 4096
  float* nzT   = awfwT + 4096;                       // 4096
  float* ampv  = nzT + 4096;                         // 65536
  float* frqv  = ampv + 65536;                       // 65536
  float* phv   = frqv + 65536;                       // 65536

  prep_kernel<<<dim3(13), dim3(256), 0, stream>>>(
      net_w, fin_w, amp_w, frq_w, nzi_w, nzu_w, wtF4, awfwT, nzT, wfold);

  z_front<<<dim3(64), dim3(512), 0, stream>>>(
      x, wtF4, net_b, fin_b, awfwT, amp_b, frq_b, nzT, nzi_b,
      (unsigned short*)y0, ampv, frqv, phv);

  up_osc<<<dim3(8, 64), dim3(256), 0, stream>>>(
      (unsigned short*)y0, wfold, nzu_b, nzf_w, nzf_b,
      noise, ampv, frqv, phv, out);
}